// Round 1
// baseline (40693.570 us; speedup 1.0000x reference)
//
#include <hip/hip_runtime.h>
#include <math.h>

// LSTM: T=512 steps, B=64, IN=512, HID=1024, K = IN+HID = 1536.
// z[b, 4H] = [x_t, h_{t-1}] @ W + bias;  f,i,o = sigmoid, g = tanh
// c = f*c + i*g; h = o*tanh(c). Outputs: stacked h [T,B,H], hx, cx (fp32).
//
// Round 1: correct fp32 baseline. One fused kernel per timestep (512
// graph-captured launches). h_{t-1} is read from the stacked output region
// of d_out (it IS the output). c state in d_ws. Weights packed once per call
// into float4 (f,i,g,o) so the inner loop does one wave-uniform dwordx4 load
// per k. Fallback to unpacked weights if ws_size is small.

namespace {

constexpr int T_STEPS = 512;
constexpr int B = 64;
constexpr int IN = 512;
constexpr int H = 1024;
constexpr int K = IN + H;   // 1536
constexpr int CHUNK = 256;  // k-chunk staged in LDS
constexpr int PITCH = 65;   // LDS row pitch (floats): conflict-free

__device__ __forceinline__ float sigmoid_f(float x) {
  return 1.0f / (1.0f + __expf(-x));
}

// Pack weights into float4 (Wf,Wi,Wg,Wo) per (k,j); pack bias; zero c and h0.
__global__ __launch_bounds__(256) void prep_packed(
    const float* __restrict__ Wf, const float* __restrict__ Wi,
    const float* __restrict__ Wg, const float* __restrict__ Wo,
    const float* __restrict__ bf, const float* __restrict__ bi,
    const float* __restrict__ bg, const float* __restrict__ bo,
    float4* __restrict__ Wp, float4* __restrict__ b4,
    float* __restrict__ c_state, float* __restrict__ h0) {
  int idx = blockIdx.x * 256 + threadIdx.x;
  if (idx < K * H) {
    Wp[idx] = make_float4(Wf[idx], Wi[idx], Wg[idx], Wo[idx]);
  }
  if (idx < H) b4[idx] = make_float4(bf[idx], bi[idx], bg[idx], bo[idx]);
  if (idx < B * H) {
    c_state[idx] = 0.0f;
    h0[idx] = 0.0f;
  }
}

__global__ __launch_bounds__(256) void prep_small(
    const float* __restrict__ bf, const float* __restrict__ bi,
    const float* __restrict__ bg, const float* __restrict__ bo,
    float4* __restrict__ b4, float* __restrict__ c_state,
    float* __restrict__ h0) {
  int idx = blockIdx.x * 256 + threadIdx.x;
  if (idx < H) b4[idx] = make_float4(bf[idx], bi[idx], bg[idx], bo[idx]);
  if (idx < B * H) {
    c_state[idx] = 0.0f;
    h0[idx] = 0.0f;
  }
}

// One timestep. Grid = H/4 = 256 blocks, 256 threads.
// Block bi owns hidden columns j in [4*bi, 4*bi+4) for ALL 4 gates and all
// 64 batch rows. Thread: b = tid&63 (lane), jj = tid>>6 (wave id, 0..3).
// So a wave shares one j -> weight loads are wave-uniform dwordx4.
template <bool PACKED>
__global__ __launch_bounds__(256) void lstm_step(
    const float* __restrict__ x_t,     // [B][IN]
    const float* __restrict__ h_prev,  // [B][H]
    const float4* __restrict__ Wp,     // [K][H] packed (f,i,g,o)
    const float* __restrict__ Wf, const float* __restrict__ Wi,
    const float* __restrict__ Wg, const float* __restrict__ Wo,
    const float4* __restrict__ b4,  // [H]
    float* __restrict__ c_state,    // [B][H]
    float* __restrict__ h_out) {    // [B][H]
  __shared__ float comb[CHUNK * PITCH];  // [k][b], padded
  const int tid = threadIdx.x;
  const int b = tid & 63;
  const int jj = tid >> 6;
  const int j = blockIdx.x * 4 + jj;

  float af = 0.0f, ai = 0.0f, ag = 0.0f, ao = 0.0f;

  for (int kc = 0; kc < K; kc += CHUNK) {
    // Select source (chunks never straddle the x/h boundary: 512 = 2*256).
    const float* src;
    int pitch, koff;
    if (kc < IN) {
      src = x_t;
      pitch = IN;
      koff = kc;
    } else {
      src = h_prev;
      pitch = H;
      koff = kc - IN;
    }
    // Stage comb[kk][bb] = src[bb*pitch + koff + kk].
    // Iteration i: thread tid loads row bb=i, col kk=tid.
    // Global: 256 consecutive floats (coalesced). LDS write: stride PITCH=65
    // -> banks tid%32, conflict-free.
    __syncthreads();
#pragma unroll
    for (int i = 0; i < B; ++i) {
      comb[tid * PITCH + i] = src[i * pitch + koff + tid];
    }
    __syncthreads();

    if (PACKED) {
      const float4* wp = Wp + (size_t)kc * H + j;
#pragma unroll 8
      for (int k = 0; k < CHUNK; ++k) {
        float cv = comb[k * PITCH + b];
        float4 w = wp[(size_t)k * H];
        af = fmaf(cv, w.x, af);
        ai = fmaf(cv, w.y, ai);
        ag = fmaf(cv, w.z, ag);
        ao = fmaf(cv, w.w, ao);
      }
    } else {
      const float* pf = Wf + (size_t)kc * H + j;
      const float* pi = Wi + (size_t)kc * H + j;
      const float* pg = Wg + (size_t)kc * H + j;
      const float* po = Wo + (size_t)kc * H + j;
#pragma unroll 8
      for (int k = 0; k < CHUNK; ++k) {
        float cv = comb[k * PITCH + b];
        af = fmaf(cv, pf[(size_t)k * H], af);
        ai = fmaf(cv, pi[(size_t)k * H], ai);
        ag = fmaf(cv, pg[(size_t)k * H], ag);
        ao = fmaf(cv, po[(size_t)k * H], ao);
      }
    }
  }

  float4 bias = b4[j];
  float zf = af + bias.x;
  float zi = ai + bias.y;
  float zg = ag + bias.z;
  float zo = ao + bias.w;
  float f = sigmoid_f(zf);
  float i_ = sigmoid_f(zi);
  float g = tanhf(zg);  // library tanh: safe for large |z|
  float o = sigmoid_f(zo);
  int idx = b * H + j;
  float c_new = fmaf(f, c_state[idx], i_ * g);
  c_state[idx] = c_new;
  h_out[idx] = o * tanhf(c_new);
}

__global__ __launch_bounds__(256) void finalize(
    const float* __restrict__ h_last, const float* __restrict__ c_state,
    float* __restrict__ hx_out, float* __restrict__ cx_out) {
  int idx = blockIdx.x * 256 + threadIdx.x;
  if (idx < B * H) {
    hx_out[idx] = h_last[idx];
    cx_out[idx] = c_state[idx];
  }
}

}  // namespace

extern "C" void kernel_launch(void* const* d_in, const int* in_sizes, int n_in,
                              void* d_out, int out_size, void* d_ws,
                              size_t ws_size, hipStream_t stream) {
  const float* x = (const float*)d_in[0];   // [T][B][IN]
  const float* Wf = (const float*)d_in[1];  // [K][H]
  const float* bf = (const float*)d_in[2];  // [H]
  const float* Wi = (const float*)d_in[3];
  const float* bi = (const float*)d_in[4];
  const float* Wg = (const float*)d_in[5];
  const float* bg = (const float*)d_in[6];
  const float* Wo = (const float*)d_in[7];
  const float* bo = (const float*)d_in[8];
  float* out = (float*)d_out;  // stacked[T][B][H] | hx[B][H] | cx[B][H]

  // Workspace layout (packed): Wp (25.2 MB) | b4 (16 KB) | c (256 KB) | h0
  size_t need_packed = (size_t)K * H * sizeof(float4) + H * sizeof(float4) +
                       2 * (size_t)B * H * sizeof(float);
  bool packed = ws_size >= need_packed;

  char* wsp = (char*)d_ws;
  float4* Wp = nullptr;
  float4* b4;
  float* c_state;
  float* h0;
  if (packed) {
    Wp = (float4*)wsp;
    wsp += (size_t)K * H * sizeof(float4);
  }
  b4 = (float4*)wsp;
  wsp += H * sizeof(float4);
  c_state = (float*)wsp;
  wsp += (size_t)B * H * sizeof(float);
  h0 = (float*)wsp;

  if (packed) {
    prep_packed<<<(K * H + 255) / 256, 256, 0, stream>>>(
        Wf, Wi, Wg, Wo, bf, bi, bg, bo, Wp, b4, c_state, h0);
  } else {
    prep_small<<<(B * H + 255) / 256, 256, 0, stream>>>(bf, bi, bg, bo, b4,
                                                        c_state, h0);
  }

  for (int t = 0; t < T_STEPS; ++t) {
    const float* x_t = x + (size_t)t * B * IN;
    const float* h_prev =
        (t == 0) ? h0 : out + (size_t)(t - 1) * B * H;
    float* h_out = out + (size_t)t * B * H;
    if (packed) {
      lstm_step<true><<<H / 4, 256, 0, stream>>>(
          x_t, h_prev, Wp, nullptr, nullptr, nullptr, nullptr, b4, c_state,
          h_out);
    } else {
      lstm_step<false><<<H / 4, 256, 0, stream>>>(
          x_t, h_prev, nullptr, Wf, Wi, Wg, Wo, b4, c_state, h_out);
    }
  }

  finalize<<<(B * H + 255) / 256, 256, 0, stream>>>(
      out + (size_t)(T_STEPS - 1) * B * H, c_state,
      out + (size_t)T_STEPS * B * H, out + (size_t)T_STEPS * B * H + B * H);
}

// Round 2
// 13249.066 us; speedup vs baseline: 3.0714x; 3.0714x over previous
//
#include <hip/hip_runtime.h>
#include <math.h>

// Persistent-kernel fp16-MFMA LSTM. T=512, B=64, IN=512, H=1024, K=1536.
// 256 blocks (one per CU) x 256 threads (4 waves). Block bi owns h-cols
// [4*bi, 4*bi+4) for all 4 gates = 16 N-cols of the fused [K x 4H] GEMM.
// W slice (16 x 1544 fp16, padded) stays in LDS for all 512 steps.
// combined [x_t | h_{t-1}] fp16 double buffer in ws; A-fragments are loaded
// directly from global (quads of a row tile full 64B lines). c-state lives in
// owner-lane registers. One device-scope grid barrier per step (generation
// counter in ws, re-initialized by prep every launch since ws is re-poisoned).

namespace {

constexpr int T_STEPS = 512;
constexpr int B = 64;
constexpr int IN = 512;
constexpr int H = 1024;
constexpr int K = IN + H;       // 1536
constexpr int NBLK = 256;       // persistent blocks
constexpr int WPITCH = K + 8;   // 1544 halves: rows 16B-aligned, 4-bank shift

typedef __attribute__((ext_vector_type(8))) _Float16 f16x8;
typedef __attribute__((ext_vector_type(4))) float f32x4;

// Fill comb[0] = [x_0 | zeros] in fp16; zero the barrier words.
__global__ void prep(const float* __restrict__ x, _Float16* __restrict__ comb,
                     unsigned* __restrict__ bar) {
  const int k = blockIdx.x * 256 + threadIdx.x;  // 0..1535
  const int b = blockIdx.y;                      // 0..63
  _Float16 v = (_Float16)0.f;
  if (k < IN) v = (_Float16)x[(size_t)b * IN + k];  // x[t=0]
  comb[(size_t)b * K + k] = v;
  if (blockIdx.x == 0 && blockIdx.y == 0 && threadIdx.x < 2)
    bar[threadIdx.x] = 0u;
}

__global__ __launch_bounds__(256, 2) void lstm_persist(
    const float* __restrict__ x, const float* __restrict__ Wf,
    const float* __restrict__ Wi, const float* __restrict__ Wg,
    const float* __restrict__ Wo, const float* __restrict__ bf,
    const float* __restrict__ bi_, const float* __restrict__ bg,
    const float* __restrict__ bo, float* __restrict__ out,
    _Float16* __restrict__ comb, unsigned* __restrict__ bar) {
  __shared__ _Float16 Wlds[16 * WPITCH];  // 49,408 B

  const int blk = blockIdx.x;
  const int tid = threadIdx.x;
  const int j0 = blk * 4;  // this block's first h-column

  // ---- one-time: stage W slice into LDS as [n][k], n = gate*4 + jj ----
  {
    const float* wptr[4] = {Wf, Wi, Wg, Wo};
#pragma unroll
    for (int g = 0; g < 4; ++g) {
      const float* wsrc = wptr[g];
      for (int it = 0; it < K / 256; ++it) {
        const int k = it * 256 + tid;  // 0..1535
        const float4 w = *(const float4*)(wsrc + (size_t)k * H + j0);
        Wlds[(g * 4 + 0) * WPITCH + k] = (_Float16)w.x;
        Wlds[(g * 4 + 1) * WPITCH + k] = (_Float16)w.y;
        Wlds[(g * 4 + 2) * WPITCH + k] = (_Float16)w.z;
        Wlds[(g * 4 + 3) * WPITCH + k] = (_Float16)w.w;
      }
    }
  }
  __syncthreads();

  const int lane = tid & 63;
  const int wv = tid >> 6;   // wave 0..3 -> M-tile
  const int q = lane >> 4;   // quad
  const int n = lane & 15;   // MFMA row/col index
  const int m0 = wv * 16;
  const int gate = n >> 2;   // 0:f 1:i 2:g 3:o
  const int jj = n & 3;

  const float* bptr[4] = {bf, bi_, bg, bo};
  const float bias_v = bptr[gate][j0 + jj];

  float c_reg[4] = {0.f, 0.f, 0.f, 0.f};  // owner lanes (n<4): c for 4 rows

  const int arow = m0 + n;  // A row this lane reads
  unsigned* cnt = bar;
  unsigned* gen = bar + 1;

  for (int t = 0; t < T_STEPS; ++t) {
    const _Float16* cc = comb + (size_t)(t & 1) * B * K;
    _Float16* cn = comb + (size_t)((t + 1) & 1) * B * K;

    f32x4 acc = {bias_v, bias_v, bias_v, bias_v};
    const _Float16* abase = cc + (size_t)arow * K + q * 8;
    const _Float16* bbase = Wlds + (size_t)n * WPITCH + q * 8;
#pragma unroll 8
    for (int kk = 0; kk < K / 32; ++kk) {
      f16x8 af = *(const f16x8*)(abase + kk * 32);
      f16x8 bfr = *(const f16x8*)(bbase + kk * 32);
      acc = __builtin_amdgcn_mfma_f32_16x16x32_f16(af, bfr, acc, 0, 0, 0);
    }

    // ---- epilogue: apply own gate nonlinearity, gather to owner lanes ----
    float v[4];
#pragma unroll
    for (int r = 0; r < 4; ++r) {
      const float z = acc[r];
      v[r] = (gate == 2) ? tanhf(z) : 1.0f / (1.0f + expf(-z));
    }
    float vi[4], vg[4], vo[4];
#pragma unroll
    for (int r = 0; r < 4; ++r) {
      vi[r] = __shfl(v[r], (lane + 4) & 63, 64);
      vg[r] = __shfl(v[r], (lane + 8) & 63, 64);
      vo[r] = __shfl(v[r], (lane + 12) & 63, 64);
    }
    if (n < 4) {  // owner: holds f in v[], i/g/o gathered
      const int j = j0 + n;
#pragma unroll
      for (int r = 0; r < 4; ++r) {
        const int b = m0 + q * 4 + r;
        const float c = fmaf(v[r], c_reg[r], vi[r] * vg[r]);
        c_reg[r] = c;
        const float h = vo[r] * tanhf(c);
        out[(size_t)t * B * H + (size_t)b * H + j] = h;
        cn[(size_t)b * K + IN + j] = (_Float16)h;
        if (t == T_STEPS - 1) {
          out[(size_t)T_STEPS * B * H + (size_t)b * H + j] = h;        // hx
          out[(size_t)T_STEPS * B * H + B * H + (size_t)b * H + j] = c;  // cx
        }
      }
    }

    // ---- copy x[t+1] into next combined buffer's x-region ----
    if (t + 1 < T_STEPS && tid < 16) {
      const int row = blk >> 2;
      const int off = (blk & 3) * 128 + tid * 8;  // floats within the row
      const float* xs =
          x + (size_t)(t + 1) * B * IN + (size_t)row * IN + off;
      const float4 x0 = *(const float4*)xs;
      const float4 x1 = *(const float4*)(xs + 4);
      f16x8 hv;
      hv[0] = (_Float16)x0.x; hv[1] = (_Float16)x0.y;
      hv[2] = (_Float16)x0.z; hv[3] = (_Float16)x0.w;
      hv[4] = (_Float16)x1.x; hv[5] = (_Float16)x1.y;
      hv[6] = (_Float16)x1.z; hv[7] = (_Float16)x1.w;
      *(f16x8*)(cn + (size_t)row * K + off) = hv;
    }

    // ---- device-scope grid barrier (skip after last step) ----
    if (t + 1 < T_STEPS) {
      __syncthreads();  // all waves' stores issued (compiler drains vmcnt)
      if (tid == 0) {
        const unsigned g0 =
            __hip_atomic_load(gen, __ATOMIC_RELAXED, __HIP_MEMORY_SCOPE_AGENT);
        __threadfence();  // release: drain this block's stores device-wide
        const unsigned a = __hip_atomic_fetch_add(cnt, 1u, __ATOMIC_ACQ_REL,
                                                  __HIP_MEMORY_SCOPE_AGENT);
        if (a == NBLK - 1) {
          __hip_atomic_store(cnt, 0u, __ATOMIC_RELAXED,
                             __HIP_MEMORY_SCOPE_AGENT);
          __threadfence();
          __hip_atomic_fetch_add(gen, 1u, __ATOMIC_RELEASE,
                                 __HIP_MEMORY_SCOPE_AGENT);
        } else {
          while (__hip_atomic_load(gen, __ATOMIC_RELAXED,
                                   __HIP_MEMORY_SCOPE_AGENT) == g0) {
            __builtin_amdgcn_s_sleep(2);
          }
        }
        __threadfence();  // acquire: invalidate L1 (+L2 lines) before reads
      }
      __syncthreads();
    }
  }
}

}  // namespace

extern "C" void kernel_launch(void* const* d_in, const int* in_sizes, int n_in,
                              void* d_out, int out_size, void* d_ws,
                              size_t ws_size, hipStream_t stream) {
  const float* x = (const float*)d_in[0];   // [T][B][IN]
  const float* Wf = (const float*)d_in[1];  // [K][H]
  const float* bf = (const float*)d_in[2];  // [H]
  const float* Wi = (const float*)d_in[3];
  const float* bi = (const float*)d_in[4];
  const float* Wg = (const float*)d_in[5];
  const float* bg = (const float*)d_in[6];
  const float* Wo = (const float*)d_in[7];
  const float* bo = (const float*)d_in[8];
  float* out = (float*)d_out;  // stacked[T][B][H] | hx[B][H] | cx[B][H]

  // ws layout: comb[2][B][K] fp16 (393,216 B) | barrier (2 x u32)
  _Float16* comb = (_Float16*)d_ws;
  unsigned* bar =
      (unsigned*)((char*)d_ws + (size_t)2 * B * K * sizeof(_Float16));

  prep<<<dim3(K / 256, B), 256, 0, stream>>>(x, comb, bar);
  lstm_persist<<<NBLK, 256, 0, stream>>>(x, Wf, Wi, Wg, Wo, bf, bi, bg, bo,
                                         out, comb, bar);
}

// Round 3
// 9858.610 us; speedup vs baseline: 4.1277x; 1.3439x over previous
//
#include <hip/hip_runtime.h>
#include <math.h>

// Persistent fp16-MFMA LSTM, round 3. T=512, B=64, IN=512, H=1024, K=1536.
// 256 blocks x 256 threads (1 block/CU, 1 wave/SIMD). Block bi owns h-cols
// [4bi,4bi+4) for 4 gates = 16 N-cols. B-fragments live in REGISTERS for all
// 512 steps (48 x f16x8 = 192 VGPRs). Cross-block data (h double buffer, x
// staging) moves via relaxed agent-scope atomics (sc0 sc1 -> Infinity Cache,
// no L2 flush fences). Grid sync = 2-level tree barrier (32 leaves + root +
// gen), relaxed agent atomics only; release = compiler's vmcnt(0) drain at
// __syncthreads before arrival. c-state in owner-lane registers.

namespace {

constexpr int T_STEPS = 512;
constexpr int B = 64;
constexpr int IN = 512;
constexpr int H = 1024;
constexpr int K = IN + H;    // 1536
constexpr int NBLK = 256;
constexpr int NXMF = IN / 32;  // 16 x-part MFMAs
constexpr int NHMF = H / 32;   // 32 h-part MFMAs
constexpr int WPITCH = K + 8;  // one-time staging pitch (halves)

// ws layout (bytes)
constexpr size_t HBUF_OFF = 0;                                  // 2*B*H fp16
constexpr size_t XBUF_OFF = HBUF_OFF + 2ull * B * H * 2;        // 2*B*IN fp16
constexpr size_t BAR_OFF = XBUF_OFF + 2ull * B * IN * 2;        // 1056 uints
constexpr size_t COMBX_OFF = BAR_OFF + 1056ull * 4;             // T*B*IN fp16
constexpr size_t NEED_PRE = COMBX_OFF + (size_t)T_STEPS * B * IN * 2;

typedef __attribute__((ext_vector_type(8))) _Float16 f16x8;
typedef __attribute__((ext_vector_type(4))) float f32x4;

__device__ __forceinline__ f16x8 load_sc1_16B(const _Float16* p) {
  union {
    unsigned long long u[2];
    f16x8 v;
  } cv;
  const unsigned long long* q = (const unsigned long long*)p;
  cv.u[0] = __hip_atomic_load(q, __ATOMIC_RELAXED, __HIP_MEMORY_SCOPE_AGENT);
  cv.u[1] =
      __hip_atomic_load(q + 1, __ATOMIC_RELAXED, __HIP_MEMORY_SCOPE_AGENT);
  return cv.v;
}

__device__ __forceinline__ void store_sc1_h16(_Float16* p, float v) {
  union {
    _Float16 f;
    unsigned short u;
  } cv;
  cv.f = (_Float16)v;
  __hip_atomic_store((unsigned short*)p, cv.u, __ATOMIC_RELAXED,
                     __HIP_MEMORY_SCOPE_AGENT);
}

__device__ __forceinline__ void store_sc1_u32(unsigned* p, unsigned v) {
  __hip_atomic_store(p, v, __ATOMIC_RELAXED, __HIP_MEMORY_SCOPE_AGENT);
}

// Prefilled-mode prep: combx[t][b][k] = fp16(x), zero hbuf, zero barrier.
__global__ void prep_pre(const float* __restrict__ x,
                         _Float16* __restrict__ combx,
                         _Float16* __restrict__ hbuf,
                         unsigned* __restrict__ bar) {
  const size_t i = (size_t)blockIdx.x * 256 + threadIdx.x;
  if (i < (size_t)T_STEPS * B * IN) combx[i] = (_Float16)x[i];
  if (i < 2ull * B * H) hbuf[i] = (_Float16)0.f;
  if (i < 1056) bar[i] = 0u;
}

// Fallback prep: xbuf[0] = fp16(x[0]), zero hbuf, zero barrier.
__global__ void prep_fb(const float* __restrict__ x,
                        _Float16* __restrict__ xbuf,
                        _Float16* __restrict__ hbuf,
                        unsigned* __restrict__ bar) {
  const size_t i = (size_t)blockIdx.x * 256 + threadIdx.x;
  if (i < (size_t)B * IN) xbuf[i] = (_Float16)x[i];
  if (i < 2ull * B * H) hbuf[i] = (_Float16)0.f;
  if (i < 1056) bar[i] = 0u;
}

template <bool PRE>
__global__ __launch_bounds__(256, 1) void lstm_persist(
    const float* __restrict__ x, const float* __restrict__ Wf,
    const float* __restrict__ Wi, const float* __restrict__ Wg,
    const float* __restrict__ Wo, const float* __restrict__ bf,
    const float* __restrict__ bi_, const float* __restrict__ bg,
    const float* __restrict__ bo, float* __restrict__ out,
    _Float16* __restrict__ combx, _Float16* __restrict__ xbuf,
    _Float16* __restrict__ hbuf, unsigned* __restrict__ bar) {
  __shared__ _Float16 Wlds[16 * WPITCH];  // one-time staging only

  const int blk = blockIdx.x;
  const int tid = threadIdx.x;
  const int j0 = blk * 4;

  // ---- one-time: stage W slice (coalesced), then lift B-frags to regs ----
  {
    const float* wptr[4] = {Wf, Wi, Wg, Wo};
#pragma unroll
    for (int g = 0; g < 4; ++g) {
      const float* wsrc = wptr[g];
      for (int it = 0; it < K / 256; ++it) {
        const int k = it * 256 + tid;
        const float4 w = *(const float4*)(wsrc + (size_t)k * H + j0);
        Wlds[(g * 4 + 0) * WPITCH + k] = (_Float16)w.x;
        Wlds[(g * 4 + 1) * WPITCH + k] = (_Float16)w.y;
        Wlds[(g * 4 + 2) * WPITCH + k] = (_Float16)w.z;
        Wlds[(g * 4 + 3) * WPITCH + k] = (_Float16)w.w;
      }
    }
  }
  __syncthreads();

  const int lane = tid & 63;
  const int wv = tid >> 6;
  const int q = lane >> 4;
  const int n = lane & 15;
  const int m0 = wv * 16;
  const int gate = n >> 2;
  const int jj = n & 3;
  const int arow = m0 + n;

  f16x8 Bfrag[NXMF + NHMF];  // 48 frags = 192 VGPRs, resident all steps
#pragma unroll
  for (int kk = 0; kk < NXMF + NHMF; ++kk) {
    Bfrag[kk] = *(const f16x8*)(&Wlds[n * WPITCH + kk * 32 + q * 8]);
  }

  const float* bptr[4] = {bf, bi_, bg, bo};
  const float bias_v = bptr[gate][j0 + jj];

  float c_reg[4] = {0.f, 0.f, 0.f, 0.f};

  unsigned* leaf = bar + (size_t)(blk >> 3) * 32;  // 128B-spaced leaves
  unsigned* root = bar + 1024;
  unsigned* gen = bar + 1025;

  for (int t = 0; t < T_STEPS; ++t) {
    const _Float16* hb = hbuf + (size_t)(t & 1) * B * H;
    _Float16* hb_next = hbuf + (size_t)((t + 1) & 1) * B * H;

    f32x4 acc = {bias_v, bias_v, bias_v, bias_v};

    // h part: agent-scope (sc1) loads from the double buffer.
    {
      const _Float16* ab = hb + (size_t)arow * H + q * 8;
#pragma unroll
      for (int kk = 0; kk < NHMF; ++kk) {
        f16x8 af = load_sc1_16B(ab + kk * 32);
        acc = __builtin_amdgcn_mfma_f32_16x16x32_f16(af, Bfrag[NXMF + kk], acc,
                                                     0, 0, 0);
      }
    }
    // x part: cached loads (PRE) or sc1 loads from staging (fallback).
    if (PRE) {
      const _Float16* ab =
          combx + (size_t)t * B * IN + (size_t)arow * IN + q * 8;
#pragma unroll
      for (int kk = 0; kk < NXMF; ++kk) {
        f16x8 af = *(const f16x8*)(ab + kk * 32);
        acc = __builtin_amdgcn_mfma_f32_16x16x32_f16(af, Bfrag[kk], acc, 0, 0,
                                                     0);
      }
    } else {
      const _Float16* ab =
          xbuf + (size_t)(t & 1) * B * IN + (size_t)arow * IN + q * 8;
#pragma unroll
      for (int kk = 0; kk < NXMF; ++kk) {
        f16x8 af = load_sc1_16B(ab + kk * 32);
        acc = __builtin_amdgcn_mfma_f32_16x16x32_f16(af, Bfrag[kk], acc, 0, 0,
                                                     0);
      }
    }

    // ---- epilogue: gate nonlinearities, gather to owner lanes ----
    float v[4];
#pragma unroll
    for (int r = 0; r < 4; ++r) {
      const float z = acc[r];
      v[r] = (gate == 2) ? tanhf(z) : 1.0f / (1.0f + expf(-z));
    }
    float vi[4], vg[4], vo[4];
#pragma unroll
    for (int r = 0; r < 4; ++r) {
      vi[r] = __shfl(v[r], (lane + 4) & 63, 64);
      vg[r] = __shfl(v[r], (lane + 8) & 63, 64);
      vo[r] = __shfl(v[r], (lane + 12) & 63, 64);
    }
    if (n < 4) {
      const int j = j0 + n;
#pragma unroll
      for (int r = 0; r < 4; ++r) {
        const int b = m0 + q * 4 + r;
        const float c = fmaf(v[r], c_reg[r], vi[r] * vg[r]);
        c_reg[r] = c;
        const float h = vo[r] * tanhf(c);
        out[(size_t)t * B * H + (size_t)b * H + j] = h;
        store_sc1_h16(hb_next + (size_t)b * H + j, h);
        if (t == T_STEPS - 1) {
          out[(size_t)T_STEPS * B * H + (size_t)b * H + j] = h;         // hx
          out[(size_t)T_STEPS * B * H + B * H + (size_t)b * H + j] = c; // cx
        }
      }
    }

    // ---- fallback: stage x[t+1] into next buffer (sc1 stores) ----
    if (!PRE && t + 1 < T_STEPS && tid < 16) {
      _Float16* xn = xbuf + (size_t)((t + 1) & 1) * B * IN;
      const int row = blk >> 2;
      const int off = (blk & 3) * 128 + tid * 8;
      const float* xs = x + (size_t)(t + 1) * B * IN + (size_t)row * IN + off;
      const float4 x0 = *(const float4*)xs;
      const float4 x1 = *(const float4*)(xs + 4);
      float vals[8] = {x0.x, x0.y, x0.z, x0.w, x1.x, x1.y, x1.z, x1.w};
#pragma unroll
      for (int i = 0; i < 4; ++i) {
        union {
          _Float16 h[2];
          unsigned u;
        } pk;
        pk.h[0] = (_Float16)vals[2 * i];
        pk.h[1] = (_Float16)vals[2 * i + 1];
        store_sc1_u32((unsigned*)(xn + (size_t)row * IN + off + 2 * i), pk.u);
      }
    }

    // ---- tree barrier: relaxed agent atomics only, no fences ----
    if (t + 1 < T_STEPS) {
      __syncthreads();  // compiler drains vmcnt(0): sc1 stores are at IF
      if (tid == 0) {
        const unsigned a = __hip_atomic_fetch_add(
            leaf, 1u, __ATOMIC_RELAXED, __HIP_MEMORY_SCOPE_AGENT);
        if (a == 7u) {
          store_sc1_u32(leaf, 0u);  // mates are all past their add
          const unsigned r = __hip_atomic_fetch_add(
              root, 1u, __ATOMIC_RELAXED, __HIP_MEMORY_SCOPE_AGENT);
          if (r == 31u) {
            store_sc1_u32(root, 0u);
            __hip_atomic_fetch_add(gen, 1u, __ATOMIC_RELAXED,
                                   __HIP_MEMORY_SCOPE_AGENT);
          }
        }
        while (__hip_atomic_load(gen, __ATOMIC_RELAXED,
                                 __HIP_MEMORY_SCOPE_AGENT) <
               (unsigned)(t + 1)) {
          __builtin_amdgcn_s_sleep(1);
        }
      }
      __syncthreads();
    }
  }
}

}  // namespace

extern "C" void kernel_launch(void* const* d_in, const int* in_sizes, int n_in,
                              void* d_out, int out_size, void* d_ws,
                              size_t ws_size, hipStream_t stream) {
  const float* x = (const float*)d_in[0];
  const float* Wf = (const float*)d_in[1];
  const float* bf = (const float*)d_in[2];
  const float* Wi = (const float*)d_in[3];
  const float* bi = (const float*)d_in[4];
  const float* Wg = (const float*)d_in[5];
  const float* bg = (const float*)d_in[6];
  const float* Wo = (const float*)d_in[7];
  const float* bo = (const float*)d_in[8];
  float* out = (float*)d_out;

  char* ws = (char*)d_ws;
  _Float16* hbuf = (_Float16*)(ws + HBUF_OFF);
  _Float16* xbuf = (_Float16*)(ws + XBUF_OFF);
  unsigned* bar = (unsigned*)(ws + BAR_OFF);
  _Float16* combx = (_Float16*)(ws + COMBX_OFF);

  const bool pre = ws_size >= NEED_PRE;

  if (pre) {
    const size_t n = (size_t)T_STEPS * B * IN;
    prep_pre<<<(unsigned)((n + 255) / 256), 256, 0, stream>>>(x, combx, hbuf,
                                                              bar);
    lstm_persist<true><<<NBLK, 256, 0, stream>>>(
        x, Wf, Wi, Wg, Wo, bf, bi, bg, bo, out, combx, xbuf, hbuf, bar);
  } else {
    prep_fb<<<(2 * B * H + 255) / 256, 256, 0, stream>>>(x, xbuf, hbuf, bar);
    lstm_persist<false><<<NBLK, 256, 0, stream>>>(
        x, Wf, Wi, Wg, Wo, bf, bi, bg, bo, out, combx, xbuf, hbuf, bar);
  }
}